// Round 1
// baseline (207.826 us; speedup 1.0000x reference)
//
#include <hip/hip_runtime.h>

#define BB 4
#define CC 32
#define HH 480
#define WW 640
#define HWv (HH*WW)

// ---------------------------------------------------------------------------
// Kernel 1: 3x3 conv (32->8) + bias + affinity normalization, fused.
// Each thread computes 4 consecutive pixels along x.
// Output: K [B][9][H][W], K[0] = 1 - sum(a), K[1..8] = a_k = aff_k / sum|aff|
// ---------------------------------------------------------------------------
__global__ __launch_bounds__(256) void conv_gen(const float* __restrict__ kx,
                                                const float* __restrict__ Wf,
                                                const float* __restrict__ bf,
                                                float* __restrict__ K)
{
    int tid = blockIdx.x * 256 + threadIdx.x;
    const int XT = WW / 4;              // 160 thread-columns
    int x4 = tid % XT;
    int t2 = tid / XT;
    int y  = t2 % HH;
    int b  = t2 / HH;
    if (b >= BB) return;
    int x0 = x4 * 4;

    float acc[8][4];
#pragma unroll
    for (int o = 0; o < 8; ++o) {
        float bv = bf[o];
#pragma unroll
        for (int p = 0; p < 4; ++p) acc[o][p] = bv;
    }

    const float* kxb = kx + (size_t)b * CC * HWv + (size_t)y * WW + x0;
    const bool ym  = (y > 0);
    const bool yp  = (y < HH - 1);
    const bool xm  = (x0 > 0);
    const bool xpl = (x0 + 4 < WW);

    for (int c = 0; c < CC; ++c) {
        const float* pl = kxb + (size_t)c * HWv;
        float p3[3][6];
        // row y-1
        if (ym) {
            const float* r = pl - WW;
            float4 v = *reinterpret_cast<const float4*>(r);
            p3[0][0] = xm ? r[-1] : 0.f;
            p3[0][1] = v.x; p3[0][2] = v.y; p3[0][3] = v.z; p3[0][4] = v.w;
            p3[0][5] = xpl ? r[4] : 0.f;
        } else {
#pragma unroll
            for (int q = 0; q < 6; ++q) p3[0][q] = 0.f;
        }
        // row y
        {
            const float* r = pl;
            float4 v = *reinterpret_cast<const float4*>(r);
            p3[1][0] = xm ? r[-1] : 0.f;
            p3[1][1] = v.x; p3[1][2] = v.y; p3[1][3] = v.z; p3[1][4] = v.w;
            p3[1][5] = xpl ? r[4] : 0.f;
        }
        // row y+1
        if (yp) {
            const float* r = pl + WW;
            float4 v = *reinterpret_cast<const float4*>(r);
            p3[2][0] = xm ? r[-1] : 0.f;
            p3[2][1] = v.x; p3[2][2] = v.y; p3[2][3] = v.z; p3[2][4] = v.w;
            p3[2][5] = xpl ? r[4] : 0.f;
        } else {
#pragma unroll
            for (int q = 0; q < 6; ++q) p3[2][q] = 0.f;
        }

#pragma unroll
        for (int o = 0; o < 8; ++o) {
#pragma unroll
            for (int r = 0; r < 3; ++r) {
#pragma unroll
                for (int t = 0; t < 3; ++t) {
                    // uniform index -> scalar load -> SGPR operand in v_fma
                    float wv = Wf[((o * CC + c) * 3 + r) * 3 + t];
#pragma unroll
                    for (int p = 0; p < 4; ++p) acc[o][p] += wv * p3[r][p + t];
                }
            }
        }
    }

    // normalization: a = aff / sum|aff|; K0 = 1 - sum(a)
    float k0[4];
#pragma unroll
    for (int p = 0; p < 4; ++p) {
        float asum = 0.f;
#pragma unroll
        for (int o = 0; o < 8; ++o) asum += fabsf(acc[o][p]);
        float rinv = 1.0f / asum;
        float s = 0.f;
#pragma unroll
        for (int o = 0; o < 8; ++o) { acc[o][p] *= rinv; s += acc[o][p]; }
        k0[p] = 1.0f - s;
    }

    size_t base = (size_t)b * 9 * HWv + (size_t)y * WW + x0;
    *reinterpret_cast<float4*>(K + base) = make_float4(k0[0], k0[1], k0[2], k0[3]);
#pragma unroll
    for (int o = 0; o < 8; ++o) {
        *reinterpret_cast<float4*>(K + base + (size_t)(o + 1) * HWv) =
            make_float4(acc[o][0], acc[o][1], acc[o][2], acc[o][3]);
    }
}

// ---------------------------------------------------------------------------
// Kernel 2: one propagation iteration.
// x_new[i,j] = sum_k K[k][i,j] * x[i - oi_k, j - oj_k]   (zero-padded)
// OFFSETS order: (0,0),(0,1),(0,-1),(1,0),(1,1),(1,-1),(-1,0),(-1,1),(-1,-1)
// ---------------------------------------------------------------------------
__device__ __forceinline__ void load_row6(const float* r, bool rowok, bool xm,
                                          bool xpl, float o[6])
{
    if (rowok) {
        float4 v = *reinterpret_cast<const float4*>(r);
        o[0] = xm ? r[-1] : 0.f;
        o[1] = v.x; o[2] = v.y; o[3] = v.z; o[4] = v.w;
        o[5] = xpl ? r[4] : 0.f;
    } else {
#pragma unroll
        for (int q = 0; q < 6; ++q) o[q] = 0.f;
    }
}

__global__ __launch_bounds__(256) void prop(const float* __restrict__ xin,
                                            const float* __restrict__ K,
                                            float* __restrict__ xout)
{
    int tid = blockIdx.x * 256 + threadIdx.x;
    const int XT = WW / 4;
    int x4 = tid % XT;
    int t2 = tid / XT;
    int y  = t2 % HH;
    int b  = t2 / HH;
    if (b >= BB) return;
    int x0 = x4 * 4;

    const bool xm  = (x0 > 0);
    const bool xpl = (x0 + 4 < WW);

    const float* xb = xin + (size_t)b * HWv + (size_t)y * WW + x0;
    float rm[6], r0[6], rp[6];
    load_row6(xb - WW, y > 0,      xm, xpl, rm);
    load_row6(xb,      true,       xm, xpl, r0);
    load_row6(xb + WW, y < HH - 1, xm, xpl, rp);

    const float* Kb = K + (size_t)b * 9 * HWv + (size_t)y * WW + x0;
    float kv[9][4];
#pragma unroll
    for (int k = 0; k < 9; ++k) {
        float4 v = *reinterpret_cast<const float4*>(Kb + (size_t)k * HWv);
        kv[k][0] = v.x; kv[k][1] = v.y; kv[k][2] = v.z; kv[k][3] = v.w;
    }

    float out[4];
#pragma unroll
    for (int p = 0; p < 4; ++p) {
        out[p] = kv[0][p] * r0[p + 1]
               + kv[1][p] * r0[p]
               + kv[2][p] * r0[p + 2]
               + kv[3][p] * rm[p + 1]
               + kv[4][p] * rm[p]
               + kv[5][p] * rm[p + 2]
               + kv[6][p] * rp[p + 1]
               + kv[7][p] * rp[p]
               + kv[8][p] * rp[p + 2];
    }

    *reinterpret_cast<float4*>(xout + (size_t)b * HWv + (size_t)y * WW + x0) =
        make_float4(out[0], out[1], out[2], out[3]);
}

// ---------------------------------------------------------------------------
extern "C" void kernel_launch(void* const* d_in, const int* in_sizes, int n_in,
                              void* d_out, int out_size, void* d_ws, size_t ws_size,
                              hipStream_t stream) {
    const float* kx   = (const float*)d_in[0];   // [4,32,480,640]
    const float* x_in = (const float*)d_in[1];   // [4,1,480,640]
    const float* Wf   = (const float*)d_in[2];   // [8,32,3,3]
    const float* bf   = (const float*)d_in[3];   // [8]
    float* out  = (float*)d_out;                 // [4,1,480,640]
    float* ws   = (float*)d_ws;

    float* Kbuf = ws;                             // 9*4*480*640 floats = 44.2 MB
    float* xbuf = ws + (size_t)9 * BB * HWv;      // 4*480*640 floats  =  4.9 MB

    const int threads = BB * HH * (WW / 4);       // 307200
    const int blocks  = threads / 256;            // 1200

    conv_gen<<<blocks, 256, 0, stream>>>(kx, Wf, bf, Kbuf);

    const float* src = x_in;
    for (int it = 0; it < 12; ++it) {
        float* dst = (it % 2 == 0) ? xbuf : out;  // it=11 (odd) -> d_out
        prop<<<blocks, 256, 0, stream>>>(src, Kbuf, dst);
        src = dst;
    }
}

// Round 2
// 206.714 us; speedup vs baseline: 1.0054x; 1.0054x over previous
//
#include <hip/hip_runtime.h>

#define BB 4
#define CC 32
#define HH 480
#define WW 640
#define HWv (HH*WW)

// ---------------------------------------------------------------------------
// Kernel 1: 3x3 conv (32->8) + bias + affinity normalization, fused.
// Each thread computes 8 consecutive pixels along x (2 float4 + 2 edge loads
// per row, 576 FMAs per channel iteration -> weight s_loads amortized 2x).
// Output: K [B][9][H][W], K[0] = 1 - sum(a), K[1..8] = a_k = aff_k / sum|aff|
// ---------------------------------------------------------------------------
__global__ __launch_bounds__(128) void conv_gen(const float* __restrict__ kx,
                                                const float* __restrict__ Wf,
                                                const float* __restrict__ bf,
                                                float* __restrict__ K)
{
    int tid = blockIdx.x * 128 + threadIdx.x;
    const int XT = WW / 8;              // 80 thread-columns
    int x8 = tid % XT;
    int t2 = tid / XT;
    int y  = t2 % HH;
    int b  = t2 / HH;
    if (b >= BB) return;
    int x0 = x8 * 8;

    float acc[8][8];
#pragma unroll
    for (int o = 0; o < 8; ++o) {
        float bv = bf[o];
#pragma unroll
        for (int p = 0; p < 8; ++p) acc[o][p] = bv;
    }

    const float* kxb = kx + (size_t)b * CC * HWv + (size_t)y * WW + x0;
    const bool xm = (x0 > 0);
    const bool xp = (x0 + 8 < WW);

    for (int c = 0; c < CC; ++c) {
        const float* pl = kxb + (size_t)c * HWv;
#pragma unroll
        for (int r = 0; r < 3; ++r) {
            const int dy = r - 1;
            const bool rowok = (y + dy >= 0) && (y + dy < HH);
            const float* rp = pl + dy * WW;
            float row[10];
            if (rowok) {
                float4 v0 = *reinterpret_cast<const float4*>(rp);
                float4 v1 = *reinterpret_cast<const float4*>(rp + 4);
                row[0] = xm ? rp[-1] : 0.f;
                row[1] = v0.x; row[2] = v0.y; row[3] = v0.z; row[4] = v0.w;
                row[5] = v1.x; row[6] = v1.y; row[7] = v1.z; row[8] = v1.w;
                row[9] = xp ? rp[8] : 0.f;
            } else {
#pragma unroll
                for (int q = 0; q < 10; ++q) row[q] = 0.f;
            }
#pragma unroll
            for (int o = 0; o < 8; ++o) {
#pragma unroll
                for (int t = 0; t < 3; ++t) {
                    // wave-uniform index -> s_load -> SGPR operand in v_fma
                    float wv = Wf[((o * CC + c) * 3 + r) * 3 + t];
#pragma unroll
                    for (int p = 0; p < 8; ++p) acc[o][p] += wv * row[p + t];
                }
            }
        }
    }

    // normalization: a = aff / sum|aff|; K0 = 1 - sum(a)
    float k0[8];
#pragma unroll
    for (int p = 0; p < 8; ++p) {
        float asum = 0.f;
#pragma unroll
        for (int o = 0; o < 8; ++o) asum += fabsf(acc[o][p]);
        float rinv = 1.0f / asum;
        float s = 0.f;
#pragma unroll
        for (int o = 0; o < 8; ++o) { acc[o][p] *= rinv; s += acc[o][p]; }
        k0[p] = 1.0f - s;
    }

    size_t base = (size_t)b * 9 * HWv + (size_t)y * WW + x0;
    *reinterpret_cast<float4*>(K + base)     = make_float4(k0[0], k0[1], k0[2], k0[3]);
    *reinterpret_cast<float4*>(K + base + 4) = make_float4(k0[4], k0[5], k0[6], k0[7]);
#pragma unroll
    for (int o = 0; o < 8; ++o) {
        size_t pb = base + (size_t)(o + 1) * HWv;
        *reinterpret_cast<float4*>(K + pb)     = make_float4(acc[o][0], acc[o][1], acc[o][2], acc[o][3]);
        *reinterpret_cast<float4*>(K + pb + 4) = make_float4(acc[o][4], acc[o][5], acc[o][6], acc[o][7]);
    }
}

// ---------------------------------------------------------------------------
// Kernel 2: one propagation iteration (unchanged from R1).
// x_new[i,j] = sum_k K[k][i,j] * x[i - oi_k, j - oj_k]   (zero-padded)
// OFFSETS order: (0,0),(0,1),(0,-1),(1,0),(1,1),(1,-1),(-1,0),(-1,1),(-1,-1)
// ---------------------------------------------------------------------------
__device__ __forceinline__ void load_row6(const float* r, bool rowok, bool xm,
                                          bool xpl, float o[6])
{
    if (rowok) {
        float4 v = *reinterpret_cast<const float4*>(r);
        o[0] = xm ? r[-1] : 0.f;
        o[1] = v.x; o[2] = v.y; o[3] = v.z; o[4] = v.w;
        o[5] = xpl ? r[4] : 0.f;
    } else {
#pragma unroll
        for (int q = 0; q < 6; ++q) o[q] = 0.f;
    }
}

__global__ __launch_bounds__(256) void prop(const float* __restrict__ xin,
                                            const float* __restrict__ K,
                                            float* __restrict__ xout)
{
    int tid = blockIdx.x * 256 + threadIdx.x;
    const int XT = WW / 4;
    int x4 = tid % XT;
    int t2 = tid / XT;
    int y  = t2 % HH;
    int b  = t2 / HH;
    if (b >= BB) return;
    int x0 = x4 * 4;

    const bool xm  = (x0 > 0);
    const bool xpl = (x0 + 4 < WW);

    const float* xb = xin + (size_t)b * HWv + (size_t)y * WW + x0;
    float rm[6], r0[6], rp[6];
    load_row6(xb - WW, y > 0,      xm, xpl, rm);
    load_row6(xb,      true,       xm, xpl, r0);
    load_row6(xb + WW, y < HH - 1, xm, xpl, rp);

    const float* Kb = K + (size_t)b * 9 * HWv + (size_t)y * WW + x0;
    float kv[9][4];
#pragma unroll
    for (int k = 0; k < 9; ++k) {
        float4 v = *reinterpret_cast<const float4*>(Kb + (size_t)k * HWv);
        kv[k][0] = v.x; kv[k][1] = v.y; kv[k][2] = v.z; kv[k][3] = v.w;
    }

    float out[4];
#pragma unroll
    for (int p = 0; p < 4; ++p) {
        out[p] = kv[0][p] * r0[p + 1]
               + kv[1][p] * r0[p]
               + kv[2][p] * r0[p + 2]
               + kv[3][p] * rm[p + 1]
               + kv[4][p] * rm[p]
               + kv[5][p] * rm[p + 2]
               + kv[6][p] * rp[p + 1]
               + kv[7][p] * rp[p]
               + kv[8][p] * rp[p + 2];
    }

    *reinterpret_cast<float4*>(xout + (size_t)b * HWv + (size_t)y * WW + x0) =
        make_float4(out[0], out[1], out[2], out[3]);
}

// ---------------------------------------------------------------------------
extern "C" void kernel_launch(void* const* d_in, const int* in_sizes, int n_in,
                              void* d_out, int out_size, void* d_ws, size_t ws_size,
                              hipStream_t stream) {
    const float* kx   = (const float*)d_in[0];   // [4,32,480,640]
    const float* x_in = (const float*)d_in[1];   // [4,1,480,640]
    const float* Wf   = (const float*)d_in[2];   // [8,32,3,3]
    const float* bf   = (const float*)d_in[3];   // [8]
    float* out  = (float*)d_out;                 // [4,1,480,640]
    float* ws   = (float*)d_ws;

    float* Kbuf = ws;                             // 9*4*480*640 floats = 44.2 MB
    float* xbuf = ws + (size_t)9 * BB * HWv;      // 4*480*640 floats  =  4.9 MB

    // conv: 8 px/thread, block=128 -> 1200 blocks (good CU packing)
    const int cthreads = BB * HH * (WW / 8);      // 153600
    conv_gen<<<cthreads / 128, 128, 0, stream>>>(kx, Wf, bf, Kbuf);

    // prop: 4 px/thread, block=256 -> 1200 blocks
    const int pthreads = BB * HH * (WW / 4);      // 307200
    const int pblocks  = pthreads / 256;          // 1200

    const float* src = x_in;
    for (int it = 0; it < 12; ++it) {
        float* dst = (it % 2 == 0) ? xbuf : out;  // it=11 (odd) -> d_out
        prop<<<pblocks, 256, 0, stream>>>(src, Kbuf, dst);
        src = dst;
    }
}